// Round 10
// baseline (1172.002 us; speedup 1.0000x reference)
//
#include <hip/hip_runtime.h>
#include <hip/hip_fp16.h>
#include <hip/hip_cooperative_groups.h>

namespace cg = cooperative_groups;

#define N_NODES 100000
#define N_EDGES 3200000
#define NPAD 100096   // row-padded node count (multiple of 128)

#define NBLK_P 320
#define SLICE4 (N_EDGES / 4 / NBLK_P)   // 2500 int4 per partition block (exact)
#define RSHIFT 15                        // src range = src>>15 : 0..3 (4.2MB fp16 slice)
#define NR 4
#define KEYN 1024                        // key = (range<<8) | (dst>>9), db<=195
#define EL_CAP 6144                      // LDS edge cache; mean full-range bucket = 5350

#define NBLK_G 768                       // cooperative grid: 3 blocks/CU guaranteed
#define NPB 131                          // 768*131 = 100608 >= N_NODES

using f16x8 = __attribute__((ext_vector_type(8))) _Float16;
using f32x4 = __attribute__((ext_vector_type(4))) float;

// ================= CSR build: (src-range, dst) two-level counting sort =================
// packed edge int: src | (dst&511)<<17   (src<2^17, dloc<2^9 -> 26 bits)

__global__ __launch_bounds__(256) void k_coarse_hist(const int4* __restrict__ src4,
                                                     const int4* __restrict__ dst4,
                                                     int* __restrict__ BH) {
    __shared__ int h[KEYN];
    int t = threadIdx.x;
    for (int i = t; i < KEYN; i += 256) h[i] = 0;
    __syncthreads();
    int base = blockIdx.x * SLICE4;
    for (int i = t; i < SLICE4; i += 256) {
        int4 s = src4[base + i];
        int4 d = dst4[base + i];
        atomicAdd(&h[((s.x >> RSHIFT) << 8) | (d.x >> 9)], 1);
        atomicAdd(&h[((s.y >> RSHIFT) << 8) | (d.y >> 9)], 1);
        atomicAdd(&h[((s.z >> RSHIFT) << 8) | (d.z >> 9)], 1);
        atomicAdd(&h[((s.w >> RSHIFT) << 8) | (d.w >> 9)], 1);
    }
    __syncthreads();
    for (int i = t; i < KEYN; i += 256) BH[blockIdx.x * KEYN + i] = h[i];
}

// column scan over 1024 keys -> keyStart + per-(block,key) placement cursors
__global__ __launch_bounds__(1024) void k_colscan(int* __restrict__ BH,
                                                  int* __restrict__ keyStart,
                                                  int* __restrict__ rowstartC) {
    __shared__ int s[1024];
    int t = threadIdx.x;
    int tot = 0;
    for (int r = 0; r < NBLK_P; ++r) tot += BH[r * KEYN + t];
    s[t] = tot;
    __syncthreads();
    for (int off = 1; off < 1024; off <<= 1) {
        int v = (t >= off) ? s[t - off] : 0;
        __syncthreads();
        s[t] += v;
        __syncthreads();
    }
    int excl = s[t] - tot;
    keyStart[t] = excl;
    if (t == 1023) {
        keyStart[KEYN] = s[t];                 // == N_EDGES
        rowstartC[NR * N_NODES] = N_EDGES;     // global CSR terminator
    }
    int run = excl;
    for (int r = 0; r < NBLK_P; ++r) {
        int v = BH[r * KEYN + t];
        BH[r * KEYN + t] = run;
        run += v;
    }
}

__global__ __launch_bounds__(256) void k_partition(const int4* __restrict__ src4,
                                                   const int4* __restrict__ dst4,
                                                   const int* __restrict__ BH,
                                                   int* __restrict__ sorted) {
    __shared__ int cur[KEYN];
    int t = threadIdx.x;
    for (int i = t; i < KEYN; i += 256) cur[i] = BH[blockIdx.x * KEYN + i];
    __syncthreads();
    int base = blockIdx.x * SLICE4;
    for (int i = t; i < SLICE4; i += 256) {
        int4 d = dst4[base + i];
        int4 s = src4[base + i];
        int p;
        p = atomicAdd(&cur[((s.x >> RSHIFT) << 8) | (d.x >> 9)], 1);
        sorted[p] = s.x | ((d.x & 511) << 17);
        p = atomicAdd(&cur[((s.y >> RSHIFT) << 8) | (d.y >> 9)], 1);
        sorted[p] = s.y | ((d.y & 511) << 17);
        p = atomicAdd(&cur[((s.z >> RSHIFT) << 8) | (d.z >> 9)], 1);
        sorted[p] = s.z | ((d.z & 511) << 17);
        p = atomicAdd(&cur[((s.w >> RSHIFT) << 8) | (d.w >> 9)], 1);
        sorted[p] = s.w | ((d.w & 511) << 17);
    }
}

// per-(range, dst-bucket): fine hist + scan -> rowstartC, scatter srcs into csr_src
__global__ __launch_bounds__(256) void k_fine(const int* __restrict__ sorted,
                                              const int* __restrict__ keyStart,
                                              int* __restrict__ rowstartC,
                                              int* __restrict__ csr_src) {
    __shared__ int eL[EL_CAP];
    __shared__ int h[512];
    __shared__ int pairsc[256];
    __shared__ int offs[512];
    int t = threadIdx.x;
    int db = blockIdx.x;   // 0..195
    int rr = blockIdx.y;   // 0..3
    int key = (rr << 8) | db;
    int beg = keyStart[key], end = keyStart[key + 1];
    int cnt = end - beg;
    bool inL = (cnt <= EL_CAP);
    h[t] = 0; h[t + 256] = 0;
    __syncthreads();
    if (inL) {
        for (int i = t; i < cnt; i += 256) eL[i] = sorted[beg + i];
        __syncthreads();
        for (int i = t; i < cnt; i += 256) atomicAdd(&h[eL[i] >> 17], 1);
    } else {
        for (int i = beg + t; i < end; i += 256) atomicAdd(&h[sorted[i] >> 17], 1);
    }
    __syncthreads();
    int pv = h[2 * t] + h[2 * t + 1];
    pairsc[t] = pv;
    __syncthreads();
    for (int off = 1; off < 256; off <<= 1) {
        int v = (t >= off) ? pairsc[t - off] : 0;
        __syncthreads();
        pairsc[t] += v;
        __syncthreads();
    }
    int e0 = pairsc[t] - pv;
    offs[2 * t] = e0;
    offs[2 * t + 1] = e0 + h[2 * t];
    __syncthreads();
    int n0 = db << 9;
    int nvalid = N_NODES - n0;
    if (nvalid > 512) nvalid = 512;
    long long rb = (long long)rr * N_NODES;
#pragma unroll
    for (int q = 0; q < 2; ++q) {
        int local = t + q * 256;
        if (local < nvalid) rowstartC[rb + n0 + local] = beg + offs[local];
    }
    __syncthreads();
    if (inL) {
        for (int i = t; i < cnt; i += 256) {
            int pk = eL[i];
            int p = atomicAdd(&offs[pk >> 17], 1);
            csr_src[beg + p] = pk & 0x1FFFF;
        }
    } else {
        for (int i = beg + t; i < end; i += 256) {
            int pk = sorted[i];
            int p = atomicAdd(&offs[pk >> 17], 1);
            csr_src[beg + p] = pk & 0x1FFFF;
        }
    }
}

// degree (sum over ranges) -> dinv; fused x -> fp16 dinv-scaled xs
__global__ __launch_bounds__(256) void k_dinv_scale(const int* __restrict__ rowstartC,
                                                    const float4* __restrict__ x4,
                                                    float* __restrict__ dinv,
                                                    int2* __restrict__ xs2) {
    __shared__ float dl[64];
    int t = threadIdx.x;
    int nb = blockIdx.x * 64;
    if (t < 64) {
        int n = nb + t;
        if (n < N_NODES) {
            int deg = 0;
#pragma unroll
            for (int r = 0; r < NR; ++r) {
                long long rb = (long long)r * N_NODES + n;
                deg += rowstartC[rb + 1] - rowstartC[rb];
            }
            float dv = rsqrtf((float)(deg + 1));
            dl[t] = dv;
            dinv[n] = dv;
        }
    }
    __syncthreads();
    for (int i = t; i < 64 * 16; i += 256) {
        int local = i >> 4, q = i & 15;
        int n = nb + local;
        if (n < N_NODES) {
            float d = dl[local];
            float4 v = x4[(long long)n * 16 + q];
            __half2 lo = __float22half2_rn(make_float2(v.x * d, v.y * d));
            __half2 hi = __float22half2_rn(make_float2(v.z * d, v.w * d));
            xs2[(long long)n * 16 + q] = make_int2(*(int*)&lo, *(int*)&hi);
        }
    }
}

// ---------------- cooperative phase-locked gather ----------------
// accS[NPB][64] f32 in LDS persists across the NR src-range passes (grid.sync between).

__device__ __forceinline__ void coop_gather_body(
    const int* __restrict__ rsC, const int* __restrict__ csr,
    const int4* __restrict__ xs16, float (*accS)[64], int nbase, int cnt)
{
    int t = threadIdx.x;
    // init: self-loop rows (pre-scaled fp16)
    for (int i = t; i < cnt * 8; i += 256) {
        int local = i >> 3, q = i & 7;
        int4 v = xs16[((long long)(nbase + local) << 3) + q];
        float2 f0 = __half22float2(*(__half2*)&v.x);
        float2 f1 = __half22float2(*(__half2*)&v.y);
        float2 f2 = __half22float2(*(__half2*)&v.z);
        float2 f3 = __half22float2(*(__half2*)&v.w);
        float* row = &accS[local][q * 8];
        row[0] = f0.x; row[1] = f0.y; row[2] = f1.x; row[3] = f1.y;
        row[4] = f2.x; row[5] = f2.y; row[6] = f3.x; row[7] = f3.y;
    }
    __syncthreads();
    int lane = t & 63, wv = t >> 6, q = lane & 7, eg = lane >> 3;
    cg::grid_group grid = cg::this_grid();
    for (int r = 0; r < NR; ++r) {
        long long rb = (long long)r * N_NODES;
        for (int ni = wv; ni < cnt; ni += 4) {
            int node = nbase + ni;
            int beg = rsC[rb + node];
            int deg = rsC[rb + node + 1] - beg;
            if (deg == 0) continue;
            float acc[8];
#pragma unroll
            for (int k = 0; k < 8; ++k) acc[k] = 0.f;
            for (int base = 0; base < deg; base += 64) {
                int rem = deg - base;
                if (rem > 64) rem = 64;
                int mye = (lane < rem) ? __builtin_nontemporal_load(&csr[beg + base + lane]) : 0;
                int nj = (rem + 7) >> 3;
                for (int j = 0; j < nj; ++j) {
                    int eidx = (j << 3) + eg;
                    int s = __shfl(mye, eidx);
                    if (eidx < rem) {
                        int4 v = xs16[((long long)s << 3) + q];
                        float2 f0 = __half22float2(*(__half2*)&v.x);
                        float2 f1 = __half22float2(*(__half2*)&v.y);
                        float2 f2 = __half22float2(*(__half2*)&v.z);
                        float2 f3 = __half22float2(*(__half2*)&v.w);
                        acc[0] += f0.x; acc[1] += f0.y; acc[2] += f1.x; acc[3] += f1.y;
                        acc[4] += f2.x; acc[5] += f2.y; acc[6] += f3.x; acc[7] += f3.y;
                    }
                }
            }
#pragma unroll
            for (int k = 0; k < 8; ++k) {
                acc[k] += __shfl_xor(acc[k], 8);
                acc[k] += __shfl_xor(acc[k], 16);
                acc[k] += __shfl_xor(acc[k], 32);
            }
            if (eg == 0) {
                float* row = &accS[ni][q * 8];
#pragma unroll
                for (int k = 0; k < 8; ++k) row[k] += acc[k];
            }
        }
        if (r < NR - 1) grid.sync();   // phase-lock: all blocks move slices together
    }
    __syncthreads();
}

// layer-1: write fp16 dinv-scaled rows
__global__ __launch_bounds__(256) void k_coop_gather_h16(
    const int* __restrict__ rsC, const int* __restrict__ csr,
    const float* __restrict__ dinv, const int4* __restrict__ xs16,
    int4* __restrict__ aggh)
{
    __shared__ float accS[NPB][64];
    int nbase = blockIdx.x * NPB;
    int cnt = N_NODES - nbase;
    if (cnt > NPB) cnt = NPB;
    coop_gather_body(rsC, csr, xs16, accS, nbase, cnt);
    int t = threadIdx.x;
    for (int i = t; i < cnt * 8; i += 256) {
        int local = i >> 3, q = i & 7;
        int n = nbase + local;
        float d = dinv[n];
        float* row = &accS[local][q * 8];
        __half2 h0 = __float22half2_rn(make_float2(d * row[0], d * row[1]));
        __half2 h1 = __float22half2_rn(make_float2(d * row[2], d * row[3]));
        __half2 h2 = __float22half2_rn(make_float2(d * row[4], d * row[5]));
        __half2 h3 = __float22half2_rn(make_float2(d * row[6], d * row[7]));
        int4 o;
        o.x = *(int*)&h0; o.y = *(int*)&h1; o.z = *(int*)&h2; o.w = *(int*)&h3;
        aggh[((long long)n << 3) + q] = o;
    }
}

// layer-2: write f32 out with dinv scale + bias
__global__ __launch_bounds__(256) void k_coop_gather_f32(
    const int* __restrict__ rsC, const int* __restrict__ csr,
    const float* __restrict__ dinv, const int4* __restrict__ xs16,
    const float4* __restrict__ bias4, float4* __restrict__ out4)
{
    __shared__ float accS[NPB][64];
    int nbase = blockIdx.x * NPB;
    int cnt = N_NODES - nbase;
    if (cnt > NPB) cnt = NPB;
    coop_gather_body(rsC, csr, xs16, accS, nbase, cnt);
    int t = threadIdx.x;
    for (int i = t; i < cnt * 16; i += 256) {
        int local = i >> 4, q = i & 15;
        int n = nbase + local;
        float d = dinv[n];
        float4 b = bias4[q];
        float* row = &accS[local][q * 4];
        out4[(long long)n * 16 + q] =
            make_float4(d * row[0] + b.x, d * row[1] + b.y, d * row[2] + b.z, d * row[3] + b.w);
    }
}

// ---------------- MFMA fused GEMM: P = fp16(dinv * (relu(A@W1 + b1) @ W2)) ----------------

#define GEMM_GROUPS 2
__global__ __launch_bounds__(256) void k_mfma_gemm(
    const f16x8* __restrict__ aggh8, const float* __restrict__ W1,
    const float* __restrict__ b1g, const float* __restrict__ W2,
    const float* __restrict__ dinv, _Float16* __restrict__ P)
{
    __shared__ _Float16 sW1T[128][72];
    __shared__ _Float16 sW2T[64][136];
    __shared__ _Float16 sH[4][16][136];
    int tid = threadIdx.x;
    for (int i = tid; i < 64 * 128; i += 256) {
        int k = i >> 7, c = i & 127;
        sW1T[c][k] = (_Float16)W1[i];
    }
    for (int i = tid; i < 128 * 64; i += 256) {
        int k = i >> 6, c = i & 63;
        sW2T[c][k] = (_Float16)W2[i];
    }
    __syncthreads();
    int w = tid >> 6;
    int l = tid & 63;
    int lr = l & 15;
    int lk = l >> 4;

    for (int g = 0; g < GEMM_GROUPS; ++g) {
        int base = blockIdx.x * (64 * GEMM_GROUPS) + (w * GEMM_GROUPS + g) * 16;
        int row = base + lr;
        f16x8 a0 = aggh8[(long long)row * 8 + lk];
        f16x8 a1 = aggh8[(long long)row * 8 + 4 + lk];
        for (int nt = 0; nt < 8; ++nt) {
            f32x4 acc = {0.f, 0.f, 0.f, 0.f};
            f16x8 bf0 = *(const f16x8*)&sW1T[nt * 16 + lr][lk * 8];
            f16x8 bf1 = *(const f16x8*)&sW1T[nt * 16 + lr][32 + lk * 8];
            acc = __builtin_amdgcn_mfma_f32_16x16x32_f16(a0, bf0, acc, 0, 0, 0);
            acc = __builtin_amdgcn_mfma_f32_16x16x32_f16(a1, bf1, acc, 0, 0, 0);
            float bb = b1g[nt * 16 + lr];
#pragma unroll
            for (int r = 0; r < 4; ++r)
                sH[w][4 * lk + r][nt * 16 + lr] = (_Float16)fmaxf(acc[r] + bb, 0.f);
        }
        f16x8 ha[4];
#pragma unroll
        for (int ks = 0; ks < 4; ++ks)
            ha[ks] = *(const f16x8*)&sH[w][lr][ks * 32 + lk * 8];
        float dv[4];
#pragma unroll
        for (int r = 0; r < 4; ++r) dv[r] = dinv[base + 4 * lk + r];
        for (int nt = 0; nt < 4; ++nt) {
            f32x4 acc = {0.f, 0.f, 0.f, 0.f};
#pragma unroll
            for (int ks = 0; ks < 4; ++ks) {
                f16x8 bf = *(const f16x8*)&sW2T[nt * 16 + lr][ks * 32 + lk * 8];
                acc = __builtin_amdgcn_mfma_f32_16x16x32_f16(ha[ks], bf, acc, 0, 0, 0);
            }
#pragma unroll
            for (int r = 0; r < 4; ++r) {
                int rr = base + 4 * lk + r;
                if (rr < N_NODES)
                    P[(long long)rr * 64 + nt * 16 + lr] = (_Float16)(dv[r] * acc[r]);
            }
        }
    }
}

// ---------------- launch ----------------

extern "C" void kernel_launch(void* const* d_in, const int* in_sizes, int n_in,
                              void* d_out, int out_size, void* d_ws, size_t ws_size,
                              hipStream_t stream) {
    const float* x  = (const float*)d_in[0];
    const int*   ei = (const int*)d_in[1];
    const float* W1 = (const float*)d_in[2];
    const float* b1 = (const float*)d_in[3];
    const float* W2 = (const float*)d_in[4];
    const float* b2 = (const float*)d_in[5];
    float* out = (float*)d_out;

    const int* srcE = ei;            // edge_index[0]
    const int* dstE = ei + N_EDGES;  // edge_index[1]

    // workspace layout
    char* w = (char*)d_ws;
    int*   blockHist = (int*)w;   w += sizeof(int) * NBLK_P * KEYN;
    int*   keyStart  = (int*)w;   w += sizeof(int) * (KEYN + 1);
    int*   rowstartC = (int*)w;   w += sizeof(int) * (NR * N_NODES + 8);
    float* dinv      = (float*)w; w += sizeof(float) * (NPAD + 128);
    int*   csr_src   = (int*)w;   w += sizeof(int) * N_EDGES;
    char*  xsbuf     = w;         w += 128 * (size_t)NPAD;   // [N][64] fp16
    // union: sorted (E ints) dies before aggh (NPAD rows fp16) is written
    char*  ubuf      = w;         w += 128 * (size_t)NPAD;
    int*   sorted = (int*)ubuf;
    int4*  aggh   = (int4*)ubuf;
    int4*  xs     = (int4*)xsbuf;
    _Float16* p2  = (_Float16*)xsbuf;  // xs dead after layer-1 gather

    // CSR build sorted by (src-range, dst)
    k_coarse_hist<<<NBLK_P, 256, 0, stream>>>((const int4*)srcE, (const int4*)dstE, blockHist);
    k_colscan<<<1, 1024, 0, stream>>>(blockHist, keyStart, rowstartC);
    k_partition<<<NBLK_P, 256, 0, stream>>>((const int4*)srcE, (const int4*)dstE,
                                            blockHist, sorted);
    k_fine<<<dim3(196, NR), 256, 0, stream>>>(sorted, keyStart, rowstartC, csr_src);
    k_dinv_scale<<<(N_NODES + 63) / 64, 256, 0, stream>>>(rowstartC, (const float4*)x,
                                                          dinv, (int2*)xsbuf);

    // layer 1: cooperative phase-locked gather -> fp16 aggh; then MFMA GEMMs -> p2
    {
        const int* a0 = rowstartC; const int* a1 = csr_src;
        const float* a2 = dinv; const int4* a3 = xs; int4* a4 = aggh;
        void* args[] = {&a0, &a1, &a2, &a3, &a4};
        hipLaunchCooperativeKernel(k_coop_gather_h16, dim3(NBLK_G), dim3(256),
                                   args, 0, stream);
    }
    k_mfma_gemm<<<NPAD / 128, 256, 0, stream>>>((const f16x8*)aggh, W1, b1, W2, dinv, p2);

    // layer 2: cooperative gather of p2 into out (+b2)
    {
        const int* a0 = rowstartC; const int* a1 = csr_src;
        const float* a2 = dinv; const int4* a3 = (const int4*)p2;
        const float4* a4 = (const float4*)b2; float4* a5 = (float4*)out;
        void* args[] = {&a0, &a1, &a2, &a3, &a4, &a5};
        hipLaunchCooperativeKernel(k_coop_gather_f32, dim3(NBLK_G), dim3(256),
                                   args, 0, stream);
    }
}

// Round 12
// 282.971 us; speedup vs baseline: 4.1418x; 4.1418x over previous
//
#include <hip/hip_runtime.h>
#include <hip/hip_fp16.h>

#define N_NODES 100000
#define N_EDGES 3200000
#define NPAD 100096   // row-padded node count (multiple of 128)

#define NBLK_P 320
#define SLICE4 (N_EDGES / 4 / NBLK_P)       // 2500 int4 per partition block (exact)
#define NBKT 512
#define BSHIFT 8                             // 256 nodes per coarse bucket
#define NBKT_USED ((N_NODES + 255) / 256)    // 391
#define EL_CAP 12288                         // LDS edge cache (48 KB); mean bucket = 8184

using f16x8 = __attribute__((ext_vector_type(8))) _Float16;
using f32x4 = __attribute__((ext_vector_type(4))) float;
using i32x4 = __attribute__((ext_vector_type(4))) int;

// ================= CSR build: two-level counting sort by dst (no global atomics) =================
// packed edge int: src | (dst&255)<<17   (src<2^17, dloc<2^8)

__global__ __launch_bounds__(256) void k_coarse_hist(const int4* __restrict__ dst4,
                                                     int* __restrict__ blockHist) {
    __shared__ int h[NBKT];
    int t = threadIdx.x;
    h[t] = 0; h[t + 256] = 0;
    __syncthreads();
    int base = blockIdx.x * SLICE4;
    for (int i = t; i < SLICE4; i += 256) {
        int4 d = dst4[base + i];
        atomicAdd(&h[d.x >> BSHIFT], 1);
        atomicAdd(&h[d.y >> BSHIFT], 1);
        atomicAdd(&h[d.z >> BSHIFT], 1);
        atomicAdd(&h[d.w >> BSHIFT], 1);
    }
    __syncthreads();
    blockHist[blockIdx.x * NBKT + t] = h[t];
    blockHist[blockIdx.x * NBKT + t + 256] = h[t + 256];
}

__global__ __launch_bounds__(1024) void k_colscan(int* __restrict__ blockHist,
                                                  int* __restrict__ coarseStart) {
    __shared__ int part[2][NBKT];
    __shared__ int s[NBKT];
    __shared__ int totA[NBKT];
    int tid = threadIdx.x;
    int b = tid & 511, q = tid >> 9;
    const int QR = NBLK_P / 2;  // 160
    int sum = 0;
    for (int r = q * QR; r < (q + 1) * QR; ++r) sum += blockHist[r * NBKT + b];
    part[q][b] = sum;
    __syncthreads();
    if (q == 0) {
        int tot = part[0][b] + part[1][b];
        s[b] = tot;
        totA[b] = tot;
    }
    __syncthreads();
    for (int off = 1; off < NBKT; off <<= 1) {
        int v = 0;
        if (q == 0 && b >= off) v = s[b - off];
        __syncthreads();
        if (q == 0) s[b] += v;
        __syncthreads();
    }
    int excl = s[b] - totA[b];
    if (q == 0) {
        coarseStart[b] = excl;
        if (b == 0) coarseStart[NBKT] = N_EDGES;
    }
    int run = excl;
    if (q == 1) run += part[0][b];
    for (int r = q * QR; r < (q + 1) * QR; ++r) {
        int v = blockHist[r * NBKT + b];
        blockHist[r * NBKT + b] = run;
        run += v;
    }
}

__global__ __launch_bounds__(256) void k_partition(const int4* __restrict__ src4,
                                                   const int4* __restrict__ dst4,
                                                   const int* __restrict__ blockHist,
                                                   int* __restrict__ sorted) {
    __shared__ int cur[NBKT];
    int t = threadIdx.x;
    cur[t] = blockHist[blockIdx.x * NBKT + t];
    cur[t + 256] = blockHist[blockIdx.x * NBKT + t + 256];
    __syncthreads();
    int base = blockIdx.x * SLICE4;
    for (int i = t; i < SLICE4; i += 256) {
        int4 d = dst4[base + i];
        int4 s = src4[base + i];
        int p;
        p = atomicAdd(&cur[d.x >> BSHIFT], 1); sorted[p] = s.x | ((d.x & 255) << 17);
        p = atomicAdd(&cur[d.y >> BSHIFT], 1); sorted[p] = s.y | ((d.y & 255) << 17);
        p = atomicAdd(&cur[d.z >> BSHIFT], 1); sorted[p] = s.z | ((d.z & 255) << 17);
        p = atomicAdd(&cur[d.w >> BSHIFT], 1); sorted[p] = s.w | ((d.w & 255) << 17);
    }
}

// per-bucket: fine hist + scan -> rowstart/dinv, scatter srcs, fused x->fp16 scale
__global__ __launch_bounds__(256) void k_fine(const int* __restrict__ sorted,
                                              const int* __restrict__ coarseStart,
                                              const float4* __restrict__ x4,
                                              int* __restrict__ rowstart,
                                              float* __restrict__ dinvg,
                                              int* __restrict__ csr_src,
                                              int2* __restrict__ xs2) {
    __shared__ int eL[EL_CAP];
    __shared__ int h[256];
    __shared__ int pairsc[256];
    __shared__ int offs[256];
    __shared__ float dloc[256];
    int t = threadIdx.x;
    int bkt = blockIdx.x;
    int beg = coarseStart[bkt], end = coarseStart[bkt + 1];
    int cnt = end - beg;
    bool inLds = (cnt <= EL_CAP);
    h[t] = 0;
    __syncthreads();
    if (inLds) {
        for (int i = t; i < cnt; i += 256) eL[i] = sorted[beg + i];
        __syncthreads();
        for (int i = t; i < cnt; i += 256) atomicAdd(&h[eL[i] >> 17], 1);
    } else {
        for (int i = beg + t; i < end; i += 256) atomicAdd(&h[sorted[i] >> 17], 1);
    }
    __syncthreads();
    int pv = h[t];
    pairsc[t] = pv;
    __syncthreads();
    for (int off = 1; off < 256; off <<= 1) {
        int v = (t >= off) ? pairsc[t - off] : 0;
        __syncthreads();
        pairsc[t] += v;
        __syncthreads();
    }
    int e0 = pairsc[t] - pv;  // exclusive
    offs[t] = e0;
    int n0 = bkt << BSHIFT;
    int nvalid = N_NODES - n0;
    if (nvalid > 256) nvalid = 256;
    if (t < nvalid) {
        rowstart[n0 + t] = beg + e0;
        float dv = rsqrtf((float)(pv + 1));
        dloc[t] = dv;
        dinvg[n0 + t] = dv;
    }
    if (bkt == 0 && t == 0) rowstart[N_NODES] = N_EDGES;
    __syncthreads();
    if (inLds) {
        for (int i = t; i < cnt; i += 256) {
            int pk = eL[i];
            int p = atomicAdd(&offs[pk >> 17], 1);
            csr_src[beg + p] = pk & 0x1FFFF;
        }
    } else {
        for (int i = beg + t; i < end; i += 256) {
            int pk = sorted[i];
            int p = atomicAdd(&offs[pk >> 17], 1);
            csr_src[beg + p] = pk & 0x1FFFF;
        }
    }
    // fused scale: xs[row] = fp16(dinv[row] * x[row]) for this bucket's rows
    for (int i = t; i < nvalid * 16; i += 256) {
        int local = i >> 4;
        int qq = i & 15;
        float d = dloc[local];
        float4 v = x4[(long long)(n0 + local) * 16 + qq];
        __half2 lo = __float22half2_rn(make_float2(v.x * d, v.y * d));
        __half2 hi = __float22half2_rn(make_float2(v.z * d, v.w * d));
        xs2[(long long)(n0 + local) * 16 + qq] = make_int2(*(int*)&lo, *(int*)&hi);
    }
}

// ---------------- full-row gather (fp16 rows = 128B = one line) ----------------
// 8 lanes x 16B per row, 8 edge-rows in flight per wave; NT loads on the csr stream

__device__ __forceinline__ void gather_core(
    const int* __restrict__ rowstart, const int* __restrict__ csr_src,
    const int4* __restrict__ xs16, int node, int lane, float acc[8])
{
    int qlane = lane & 7;
    int egrp = lane >> 3;
    int beg = rowstart[node];
    int deg = rowstart[node + 1] - beg;
#pragma unroll
    for (int k = 0; k < 8; ++k) acc[k] = 0.f;
    if (egrp == 0) {  // self loop (pre-scaled)
        int4 v = xs16[((long long)node << 3) + qlane];
        float2 f0 = __half22float2(*(__half2*)&v.x);
        float2 f1 = __half22float2(*(__half2*)&v.y);
        float2 f2 = __half22float2(*(__half2*)&v.z);
        float2 f3 = __half22float2(*(__half2*)&v.w);
        acc[0] = f0.x; acc[1] = f0.y; acc[2] = f1.x; acc[3] = f1.y;
        acc[4] = f2.x; acc[5] = f2.y; acc[6] = f3.x; acc[7] = f3.y;
    }
    for (int base = 0; base < deg; base += 64) {
        int rem = deg - base;
        if (rem > 64) rem = 64;
        int mye = (lane < rem) ? __builtin_nontemporal_load(&csr_src[beg + base + lane]) : 0;
        int nj = (rem + 7) >> 3;
        for (int j = 0; j < nj; ++j) {
            int eidx = (j << 3) + egrp;
            int s = __shfl(mye, eidx);
            if (eidx < rem) {
                int4 v = xs16[((long long)s << 3) + qlane];
                float2 f0 = __half22float2(*(__half2*)&v.x);
                float2 f1 = __half22float2(*(__half2*)&v.y);
                float2 f2 = __half22float2(*(__half2*)&v.z);
                float2 f3 = __half22float2(*(__half2*)&v.w);
                acc[0] += f0.x; acc[1] += f0.y; acc[2] += f1.x; acc[3] += f1.y;
                acc[4] += f2.x; acc[5] += f2.y; acc[6] += f3.x; acc[7] += f3.y;
            }
        }
    }
#pragma unroll
    for (int k = 0; k < 8; ++k) {
        acc[k] += __shfl_xor(acc[k], 8);
        acc[k] += __shfl_xor(acc[k], 16);
        acc[k] += __shfl_xor(acc[k], 32);
    }
}

// layer-1: out fp16, dinv-scaled, no bias (NT store via ext_vector)
__global__ __launch_bounds__(256) void k_gather_h16(
    const int* __restrict__ rowstart, const int* __restrict__ csr_src,
    const float* __restrict__ dinv, const int4* __restrict__ xs16,
    int4* __restrict__ aggh)
{
    int node = blockIdx.x * 4 + (threadIdx.x >> 6);
    if (node >= N_NODES) return;
    int lane = threadIdx.x & 63;
    float acc[8];
    gather_core(rowstart, csr_src, xs16, node, lane, acc);
    if ((lane >> 3) == 0) {
        float d = dinv[node];
        __half2 h0 = __float22half2_rn(make_float2(d * acc[0], d * acc[1]));
        __half2 h1 = __float22half2_rn(make_float2(d * acc[2], d * acc[3]));
        __half2 h2 = __float22half2_rn(make_float2(d * acc[4], d * acc[5]));
        __half2 h3 = __float22half2_rn(make_float2(d * acc[6], d * acc[7]));
        i32x4 o = {*(int*)&h0, *(int*)&h1, *(int*)&h2, *(int*)&h3};
        __builtin_nontemporal_store(o, (i32x4*)&aggh[((long long)node << 3) + (lane & 7)]);
    }
}

// layer-2: out f32 with dinv scale + bias (NT store via ext_vector)
__global__ __launch_bounds__(256) void k_gather_f32(
    const int* __restrict__ rowstart, const int* __restrict__ csr_src,
    const float* __restrict__ dinv, const int4* __restrict__ xs16,
    const float4* __restrict__ bias4, float4* __restrict__ out4)
{
    int node = blockIdx.x * 4 + (threadIdx.x >> 6);
    if (node >= N_NODES) return;
    int lane = threadIdx.x & 63;
    float acc[8];
    gather_core(rowstart, csr_src, xs16, node, lane, acc);
    int qlane = lane & 7;
    if ((lane >> 3) == 0) {
        float d = dinv[node];
        float4 b0 = bias4[qlane * 2];
        float4 b1 = bias4[qlane * 2 + 1];
        f32x4 o0 = {d * acc[0] + b0.x, d * acc[1] + b0.y, d * acc[2] + b0.z, d * acc[3] + b0.w};
        f32x4 o1 = {d * acc[4] + b1.x, d * acc[5] + b1.y, d * acc[6] + b1.z, d * acc[7] + b1.w};
        __builtin_nontemporal_store(o0, (f32x4*)&out4[(long long)node * 16 + qlane * 2]);
        __builtin_nontemporal_store(o1, (f32x4*)&out4[(long long)node * 16 + qlane * 2 + 1]);
    }
}

// ---------------- MFMA fused GEMM: P = fp16(dinv * (relu(A@W1 + b1) @ W2)) ----------------
// A (aggh) fp16 [N][64]; 256 thr = 4 waves; 2 groups of 16 rows per wave -> 128 rows/block.

#define GEMM_GROUPS 2
__global__ __launch_bounds__(256) void k_mfma_gemm(
    const f16x8* __restrict__ aggh8, const float* __restrict__ W1,
    const float* __restrict__ b1g, const float* __restrict__ W2,
    const float* __restrict__ dinv, _Float16* __restrict__ P)
{
    __shared__ _Float16 sW1T[128][72];
    __shared__ _Float16 sW2T[64][136];
    __shared__ _Float16 sH[4][16][136];
    int tid = threadIdx.x;
    for (int i = tid; i < 64 * 128; i += 256) {
        int k = i >> 7, c = i & 127;
        sW1T[c][k] = (_Float16)W1[i];
    }
    for (int i = tid; i < 128 * 64; i += 256) {
        int k = i >> 6, c = i & 63;
        sW2T[c][k] = (_Float16)W2[i];
    }
    __syncthreads();
    int w = tid >> 6;
    int l = tid & 63;
    int lr = l & 15;
    int lk = l >> 4;

    for (int g = 0; g < GEMM_GROUPS; ++g) {
        int base = blockIdx.x * (64 * GEMM_GROUPS) + (w * GEMM_GROUPS + g) * 16;
        int row = base + lr;
        f16x8 a0 = aggh8[(long long)row * 8 + lk];
        f16x8 a1 = aggh8[(long long)row * 8 + 4 + lk];
        for (int nt = 0; nt < 8; ++nt) {
            f32x4 acc = {0.f, 0.f, 0.f, 0.f};
            f16x8 bf0 = *(const f16x8*)&sW1T[nt * 16 + lr][lk * 8];
            f16x8 bf1 = *(const f16x8*)&sW1T[nt * 16 + lr][32 + lk * 8];
            acc = __builtin_amdgcn_mfma_f32_16x16x32_f16(a0, bf0, acc, 0, 0, 0);
            acc = __builtin_amdgcn_mfma_f32_16x16x32_f16(a1, bf1, acc, 0, 0, 0);
            float bb = b1g[nt * 16 + lr];
#pragma unroll
            for (int r = 0; r < 4; ++r)
                sH[w][4 * lk + r][nt * 16 + lr] = (_Float16)fmaxf(acc[r] + bb, 0.f);
        }
        f16x8 ha[4];
#pragma unroll
        for (int ks = 0; ks < 4; ++ks)
            ha[ks] = *(const f16x8*)&sH[w][lr][ks * 32 + lk * 8];
        float dv[4];
#pragma unroll
        for (int r = 0; r < 4; ++r) dv[r] = dinv[base + 4 * lk + r];
        for (int nt = 0; nt < 4; ++nt) {
            f32x4 acc = {0.f, 0.f, 0.f, 0.f};
#pragma unroll
            for (int ks = 0; ks < 4; ++ks) {
                f16x8 bf = *(const f16x8*)&sW2T[nt * 16 + lr][ks * 32 + lk * 8];
                acc = __builtin_amdgcn_mfma_f32_16x16x32_f16(ha[ks], bf, acc, 0, 0, 0);
            }
#pragma unroll
            for (int r = 0; r < 4; ++r) {
                int rr = base + 4 * lk + r;
                if (rr < N_NODES)
                    P[(long long)rr * 64 + nt * 16 + lr] = (_Float16)(dv[r] * acc[r]);
            }
        }
    }
}

// ---------------- launch ----------------

extern "C" void kernel_launch(void* const* d_in, const int* in_sizes, int n_in,
                              void* d_out, int out_size, void* d_ws, size_t ws_size,
                              hipStream_t stream) {
    const float* x  = (const float*)d_in[0];
    const int*   ei = (const int*)d_in[1];
    const float* W1 = (const float*)d_in[2];
    const float* b1 = (const float*)d_in[3];
    const float* W2 = (const float*)d_in[4];
    const float* b2 = (const float*)d_in[5];
    float* out = (float*)d_out;

    const int* srcE = ei;            // edge_index[0]
    const int* dstE = ei + N_EDGES;  // edge_index[1]

    // workspace layout
    char* w = (char*)d_ws;
    int*   blockHist   = (int*)w;   w += sizeof(int) * NBLK_P * NBKT;
    int*   coarseStart = (int*)w;   w += sizeof(int) * (NBKT + 1);
    int*   rowstart    = (int*)w;   w += sizeof(int) * (N_NODES + 8);
    float* dinv        = (float*)w; w += sizeof(float) * (NPAD + 128);
    int*   csr_src     = (int*)w;   w += sizeof(int) * N_EDGES;
    char*  xsbuf       = w;         w += 128 * (size_t)NPAD;   // [N][64] fp16
    // union: sorted (E ints = 12.8MB) dies before aggh (NPAD rows fp16) is written
    char*  ubuf        = w;         w += 128 * (size_t)NPAD;
    int*   sorted = (int*)ubuf;
    int4*  aggh   = (int4*)ubuf;
    int4*  xs     = (int4*)xsbuf;
    _Float16* p2  = (_Float16*)xsbuf;  // xs dead after layer-1 gather; reuse for fp16 p2

    // CSR build (no global atomics) + fused dinv/scale
    k_coarse_hist<<<NBLK_P, 256, 0, stream>>>((const int4*)dstE, blockHist);
    k_colscan<<<1, 1024, 0, stream>>>(blockHist, coarseStart);
    k_partition<<<NBLK_P, 256, 0, stream>>>((const int4*)srcE, (const int4*)dstE,
                                            blockHist, sorted);
    k_fine<<<NBKT_USED, 256, 0, stream>>>(sorted, coarseStart, (const float4*)x,
                                          rowstart, dinv, csr_src, (int2*)xsbuf);

    // layer 1: full-row gather (fp16 out), then MFMA fused GEMMs -> p2 (fp16, dinv-scaled)
    k_gather_h16<<<(N_NODES + 3) / 4, 256, 0, stream>>>(rowstart, csr_src, dinv, xs, aggh);
    k_mfma_gemm<<<NPAD / 128, 256, 0, stream>>>((const f16x8*)aggh, W1, b1, W2, dinv, p2);

    // layer 2: full-row gather into out (+b2)
    k_gather_f32<<<(N_NODES + 3) / 4, 256, 0, stream>>>(rowstart, csr_src, dinv,
                                                        (const int4*)p2,
                                                        (const float4*)b2, (float4*)out);
}